// Round 1
// baseline (277.126 us; speedup 1.0000x reference)
//
#include <hip/hip_runtime.h>

static constexpr float kIouT = 0.35f;
static constexpr float kScoreT = 0.5f;

// Bit-exact mirror of the reference IoU:
//   area = (y2-y1)*(x2-x1)
//   inter = max(iy2-iy1,0)*max(ix2-ix1,0)
//   union = area_i + area_j - inter ; iou = union>0 ? inter/union : 0
// __fmul_rn / __fdiv_rn block FMA contraction so rounding matches numpy/JAX f32.
__device__ __forceinline__ float iou_f(const float4 a, const float4 b) {
  float areaA = __fmul_rn(a.z - a.x, a.w - a.y);
  float areaB = __fmul_rn(b.z - b.x, b.w - b.y);
  float iy1 = fmaxf(a.x, b.x);
  float ix1 = fmaxf(a.y, b.y);
  float iy2 = fminf(a.z, b.z);
  float ix2 = fminf(a.w, b.w);
  float dy = fmaxf(iy2 - iy1, 0.0f);
  float dx = fmaxf(ix2 - ix1, 0.0f);
  float inter = __fmul_rn(dy, dx);
  float uni = (areaA + areaB) - inter;
  return (uni > 0.0f) ? __fdiv_rn(inter, uni) : 0.0f;
}

// ---------------- fast path: kernel 1 — per-image bitonic sort ----------------
// key = (~score_bits << 32) | idx, sorted ascending  ==  stable argsort(-scores).
__global__ __launch_bounds__(1024)
void nms_sort_kernel(const float* __restrict__ scores,
                     const float4* __restrict__ boxes,
                     unsigned long long* __restrict__ skeys,
                     float4* __restrict__ sboxes,
                     int* __restrict__ Mcnt, int N) {
  extern __shared__ unsigned long long keys[];
  __shared__ int s_m;
  const int img = blockIdx.x;
  const int tid = threadIdx.x;
  const float* sc = scores + (size_t)img * N;
  const float4* bx = boxes + (size_t)img * N;
  if (tid == 0) s_m = 0;
  __syncthreads();
  int cnt = 0;
  for (int i = tid; i < N; i += blockDim.x) {
    float s = sc[i];
    keys[i] = ((unsigned long long)(~__float_as_uint(s)) << 32) | (unsigned)i;
    if (s > kScoreT) cnt++;
  }
  if (cnt) atomicAdd(&s_m, cnt);
  __syncthreads();
  for (int k = 2; k <= N; k <<= 1) {
    for (int j = k >> 1; j > 0; j >>= 1) {
      for (int i = tid; i < N; i += blockDim.x) {
        int ixj = i ^ j;
        if (ixj > i) {
          unsigned long long a = keys[i];
          unsigned long long b = keys[ixj];
          bool up = ((i & k) == 0);
          if (up ? (a > b) : (a < b)) { keys[i] = b; keys[ixj] = a; }
        }
      }
      __syncthreads();
    }
  }
  for (int i = tid; i < N; i += blockDim.x) {
    unsigned long long ki = keys[i];
    skeys[(size_t)img * N + i] = ki;
    sboxes[(size_t)img * N + i] = bx[(unsigned)ki];
  }
  if (tid == 0) Mcnt[img] = s_m;
}

// ------------- fast path: kernel 2 — pairwise IoU suppression masks -----------
// One wave per sorted row i (valid prefix only); word w bit b set iff
// j = w*64+b satisfies j > i, j < M, iou(i,j) > 0.35.
__global__ __launch_bounds__(256)
void nms_mask_kernel(const float4* __restrict__ sboxes,
                     const int* __restrict__ Mcnt,
                     unsigned long long* __restrict__ mask,
                     int N, int totalRows) {
  const int wid = (int)(((unsigned)blockIdx.x * blockDim.x + threadIdx.x) >> 6);
  const int lane = threadIdx.x & 63;
  if (wid >= totalRows) return;
  const int img = wid / N;
  const int row = wid - img * N;
  const int m = Mcnt[img];
  if (row >= m) return;
  const float4* sb = sboxes + (size_t)img * N;
  const float4 bi = sb[row];
  const int nw = (m + 63) >> 6;
  unsigned long long* mrow = mask + (size_t)wid * (size_t)(N >> 6);
  for (int w = row >> 6; w < nw; ++w) {
    int j = (w << 6) | lane;
    bool sup = false;
    if (j > row && j < m) sup = iou_f(bi, sb[j]) > kIouT;
    unsigned long long bm = __ballot(sup);
    if (lane == 0) mrow[w] = bm;
  }
}

// ------------- fast path: kernel 3 — single-wave sequential scan --------------
// remv bitmask distributed over lanes (lane l owns word l). Per kept box:
// one coalesced 64-bit-per-lane mask-row load + OR. Early exit at NS kept.
__global__ __launch_bounds__(64)
void nms_scan_kernel(const unsigned long long* __restrict__ skeys,
                     const float4* __restrict__ sboxes,
                     const int* __restrict__ Mcnt,
                     const unsigned long long* __restrict__ mask,
                     const float* __restrict__ anchors,
                     float* __restrict__ out, int N, int NS) {
  const int img = blockIdx.x;
  const int lane = threadIdx.x;
  const int m = Mcnt[img];
  const int nw = (m + 63) >> 6;
  const unsigned long long* kg = skeys + (size_t)img * N;
  const float4* sb = sboxes + (size_t)img * N;
  const float* an = anchors + (size_t)img * N * 4;
  float* o = out + (size_t)img * NS * 7;
  unsigned long long remv = 0ull;
  int kept = 0;
  for (int i = 0; i < m && kept < NS; ++i) {
    unsigned long long rw = __shfl(remv, i >> 6, 64);
    if ((rw >> (i & 63)) & 1ull) continue;
    if (lane == 0) {
      unsigned long long ki = kg[i];
      float4 bi = sb[i];
      unsigned idx = (unsigned)ki;
      float s = __uint_as_float(~(unsigned)(ki >> 32));
      float* row = o + kept * 7;
      row[0] = s;
      row[1] = bi.x; row[2] = bi.y; row[3] = bi.z; row[4] = bi.w;
      row[5] = an[idx * 4 + 2];
      row[6] = an[idx * 4 + 3];
    }
    kept++;
    const unsigned long long* mrow =
        mask + (size_t)(img * N + i) * (size_t)(N >> 6);
    if (lane >= (i >> 6) && lane < nw) remv |= mrow[lane];
  }
  // zero the unfilled tail (disjoint from filled rows -> no intra-wave race)
  for (int t = kept * 7 + lane; t < NS * 7; t += 64) o[t] = 0.0f;
}

// --------------- fallback: fused sort + on-the-fly scan (no d_ws) -------------
__global__ __launch_bounds__(1024)
void nms_fused_kernel(const float* __restrict__ scores,
                      const float4* __restrict__ boxes,
                      const float* __restrict__ anchors,
                      float* __restrict__ out, int N, int NS) {
  __shared__ unsigned long long keys[4096];
  __shared__ int s_m;
  if (N > 4096) return;
  const int img = blockIdx.x;
  const int tid = threadIdx.x;
  const float* sc = scores + (size_t)img * N;
  const float4* bx = boxes + (size_t)img * N;
  if (tid == 0) s_m = 0;
  __syncthreads();
  int cnt = 0;
  for (int i = tid; i < N; i += blockDim.x) {
    float s = sc[i];
    keys[i] = ((unsigned long long)(~__float_as_uint(s)) << 32) | (unsigned)i;
    if (s > kScoreT) cnt++;
  }
  if (cnt) atomicAdd(&s_m, cnt);
  __syncthreads();
  for (int k = 2; k <= N; k <<= 1) {
    for (int j = k >> 1; j > 0; j >>= 1) {
      for (int i = tid; i < N; i += blockDim.x) {
        int ixj = i ^ j;
        if (ixj > i) {
          unsigned long long a = keys[i];
          unsigned long long b = keys[ixj];
          bool up = ((i & k) == 0);
          if (up ? (a > b) : (a < b)) { keys[i] = b; keys[ixj] = a; }
        }
      }
      __syncthreads();
    }
  }
  if (tid >= 64) return;  // wave 0 does the sequential scan, no more barriers
  const int lane = tid;
  const int m = s_m;
  const int nw = (m + 63) >> 6;
  const float* an = anchors + (size_t)img * N * 4;
  float* o = out + (size_t)img * NS * 7;
  unsigned long long remv = 0ull;
  int kept = 0;
  for (int i = 0; i < m && kept < NS; ++i) {
    unsigned long long rw = __shfl(remv, i >> 6, 64);
    if ((rw >> (i & 63)) & 1ull) continue;
    unsigned long long ki = keys[i];
    float4 bi = bx[(unsigned)ki];
    if (lane == 0) {
      unsigned idx = (unsigned)ki;
      float s = __uint_as_float(~(unsigned)(ki >> 32));
      float* row = o + kept * 7;
      row[0] = s;
      row[1] = bi.x; row[2] = bi.y; row[3] = bi.z; row[4] = bi.w;
      row[5] = an[idx * 4 + 2];
      row[6] = an[idx * 4 + 3];
    }
    kept++;
    for (int w2 = i >> 6; w2 < nw; ++w2) {
      int j = (w2 << 6) | lane;
      bool sup = false;
      if (j > i && j < m) sup = iou_f(bi, bx[(unsigned)keys[j]]) > kIouT;
      unsigned long long bm = __ballot(sup);
      if (lane == w2) remv |= bm;
    }
  }
  for (int t = kept * 7 + lane; t < NS * 7; t += 64) o[t] = 0.0f;
}

extern "C" void kernel_launch(void* const* d_in, const int* in_sizes, int n_in,
                              void* d_out, int out_size, void* d_ws, size_t ws_size,
                              hipStream_t stream) {
  const float* scores = (const float*)d_in[0];
  const float4* boxes = (const float4*)d_in[1];
  const float* anchors = (const float*)d_in[2];
  float* out = (float*)d_out;
  const int B = 8;
  const int N = in_sizes[0] / B;      // 4096 boxes/image
  const int NS = out_size / (B * 7);  // 300 samples

  const size_t nTot = (size_t)B * (size_t)N;
  const size_t keysB = nTot * 8;                        // sorted keys
  const size_t sboxB = nTot * 16;                       // sorted boxes
  const size_t mcntB = 256;                             // valid counts
  const size_t maskB = nTot * (size_t)(N >> 6) * 8;     // suppression masks
  const size_t need = keysB + sboxB + mcntB + maskB;

  if (ws_size >= need && (N & (N - 1)) == 0) {
    char* p = (char*)d_ws;
    unsigned long long* skeys = (unsigned long long*)p; p += keysB;
    float4* sboxes = (float4*)p;                         p += sboxB;
    int* Mcnt = (int*)p;                                 p += mcntB;
    unsigned long long* mask = (unsigned long long*)p;

    nms_sort_kernel<<<B, 1024, (size_t)N * 8, stream>>>(scores, boxes, skeys,
                                                        sboxes, Mcnt, N);
    const int totalRows = B * N;
    const int blocks = (int)(((long long)totalRows * 64 + 255) / 256);
    nms_mask_kernel<<<blocks, 256, 0, stream>>>(sboxes, Mcnt, mask, N, totalRows);
    nms_scan_kernel<<<B, 64, 0, stream>>>(skeys, sboxes, Mcnt, mask, anchors,
                                          out, N, NS);
  } else {
    nms_fused_kernel<<<B, 1024, 0, stream>>>(scores, boxes, anchors, out, N, NS);
  }
}